// Round 4
// baseline (1124.304 us; speedup 1.0000x reference)
//
#include <hip/hip_runtime.h>
#include <cstdint>

#define B_SZ 4
#define S_LEN 1024
#define DIM 4096
#define NH 32
#define KVH 8
#define HD 128
#define DQKV 6144  // 4096 Q + 1024 K + 1024 V

typedef __bf16 bf16x8 __attribute__((ext_vector_type(8)));
typedef float f32x4 __attribute__((ext_vector_type(4)));

__device__ __forceinline__ unsigned short f2bf(float f) {
  union { float f; uint32_t u; } v; v.f = f;
  uint32_t u = v.u;
  return (unsigned short)((u + 0x7fffu + ((u >> 16) & 1u)) >> 16);
}
__device__ __forceinline__ float bf2f(unsigned short h) {
  union { uint32_t u; float f; } v; v.u = ((uint32_t)h) << 16;
  return v.f;
}
__device__ __forceinline__ float ex2(float x) {
#if __has_builtin(__builtin_amdgcn_exp2f)
  return __builtin_amdgcn_exp2f(x);
#else
  return exp2f(x);
#endif
}

// async global->LDS, 16B per lane; LDS dest = wave-uniform base + lane*16
__device__ __forceinline__ void async16(void* lds, const void* g) {
  __builtin_amdgcn_global_load_lds(
      (const __attribute__((address_space(1))) void*)g,
      (__attribute__((address_space(3))) void*)lds, 16, 0, 0);
}

// ---------------- elementwise f32 -> bf16 ----------------
__global__ void cvt_x_kernel(const float* __restrict__ x, unsigned short* __restrict__ xb) {
  size_t i = ((size_t)blockIdx.x * 256 + threadIdx.x) * 4;
  float4 v = *(const float4*)(x + i);
  ushort4 o;
  o.x = f2bf(v.x); o.y = f2bf(v.y); o.z = f2bf(v.z); o.w = f2bf(v.w);
  *(ushort4*)(xb + i) = o;
}

// ---------------- weight transpose+convert: w (K x N f32) -> wt (N x K bf16, ld=4096) ----
__global__ void wtrans_kernel(const float* __restrict__ w, unsigned short* __restrict__ wt, int N) {
  __shared__ float tile[64][65];
  int n0 = blockIdx.x * 64, k0 = blockIdx.y * 64;
  int tx = threadIdx.x & 63, ty = threadIdx.x >> 6;
#pragma unroll
  for (int i = 0; i < 16; i++) {
    int k = ty + i * 4;
    tile[k][tx] = w[(size_t)(k0 + k) * N + n0 + tx];
  }
  __syncthreads();
  int c = threadIdx.x & 31, ny = threadIdx.x >> 5;
#pragma unroll
  for (int i = 0; i < 8; i++) {
    int n = ny + i * 8;
    ushort2 o;
    o.x = f2bf(tile[2 * c][n]);
    o.y = f2bf(tile[2 * c + 1][n]);
    *(ushort2*)(wt + (size_t)(n0 + n) * DIM + k0 + 2 * c) = o;
  }
}

// ---------------- GEMM: C(MxN) = A(MxK bf16) * Bt(NxK bf16)^T ----------------
// m201-style 8-phase schedule (round-2 variant, best measured of the three: 245 us QKV).
// 256x256 tile, BK=64, double-buffered 128 KiB LDS, 8 waves (2M x 4N).
template <bool OUT_BF16>
__global__ __launch_bounds__(512, 2) void gemm256_kernel(
    const unsigned short* __restrict__ A, const unsigned short* __restrict__ Bt,
    void* __restrict__ Cout, int Kdim, int ldc) {
  __shared__ __align__(16) unsigned short sh[2 * 32768];  // [buf][A 16384 | B 16384]
  const int tid = threadIdx.x;
  const int wave = tid >> 6, lane = tid & 63;
  // XCD-aware bijective block swizzle (grid size % 8 == 0 for both call sites)
  const int nbx = gridDim.x;
  const int nb = nbx * (int)gridDim.y;
  const int bid = (int)blockIdx.y * nbx + (int)blockIdx.x;
  const int sb = (bid & 7) * (nb >> 3) + (bid >> 3);
  const int m0 = (sb / nbx) * 256, n0 = (sb % nbx) * 256;

  // staging: half-tile = 128 rows x 64 elems = 1024 x 16B slots; thread covers
  // slot tid (j=0) and tid+512 (j=1). row = slot>>3, phys chunk = slot&7,
  // logical chunk = phys ^ (row&7). j=1 is row+64, same chunk bits.
  const int r0 = tid >> 3;                       // 0..63
  const int cs0 = (tid & 7) ^ (r0 & 7);
  const unsigned short* gA = A + (size_t)(m0 + r0) * Kdim + cs0 * 8;
  const unsigned short* gB = Bt + (size_t)(n0 + r0) * Kdim + cs0 * 8;
  const size_t row64 = (size_t)64 * Kdim;
  const size_t row128 = (size_t)128 * Kdim;

  // compute-side fragment addressing (16x16x32: lane row = lane&15, k-chunk = lane>>4)
  const int wm = wave >> 2, wn = wave & 3;
  const int rl = lane & 15, lh4 = lane >> 4;
  const int pc0 = (lh4 ^ (rl & 7)) * 8;          // k-half 0 phys chunk (elems)
  const int pc1 = ((lh4 + 4) ^ (rl & 7)) * 8;    // k-half 1 ( = pc0 ^ 32 )
  const int arow = (wm * 128 + rl) * 64;
  const int brow = (wn * 64 + rl) * 64;

  f32x4 acc[8][4] = {};

#define STAGEH(BUF, AB, H, GS) do {                                               \
    unsigned short* d_ = sh + (BUF) * 32768 + (AB) * 16384 + (H) * 8192 + wave * 512; \
    async16(d_, (GS));                                                            \
    async16(d_ + 4096, (GS) + row64);                                             \
  } while (0)

#define PHASEQ(Q, STAGE_STMT, WAIT_STMT) do {                                     \
    af[0][0] = *(const bf16x8*)(bufA + arow + (2 * (Q)) * 1024 + pc0);            \
    af[0][1] = *(const bf16x8*)(bufA + arow + (2 * (Q)) * 1024 + pc1);            \
    af[1][0] = *(const bf16x8*)(bufA + arow + (2 * (Q) + 1) * 1024 + pc0);        \
    af[1][1] = *(const bf16x8*)(bufA + arow + (2 * (Q) + 1) * 1024 + pc1);        \
    STAGE_STMT;                                                                   \
    WAIT_STMT;                                                                    \
    __builtin_amdgcn_s_barrier();                                                 \
    __builtin_amdgcn_s_setprio(1);                                                \
    _Pragma("unroll") for (int i = 0; i < 2; i++)                                 \
      _Pragma("unroll") for (int n = 0; n < 4; n++) {                             \
        acc[2 * (Q) + i][n] = __builtin_amdgcn_mfma_f32_16x16x32_bf16(            \
            af[i][0], bf[n][0], acc[2 * (Q) + i][n], 0, 0, 0);                    \
        acc[2 * (Q) + i][n] = __builtin_amdgcn_mfma_f32_16x16x32_bf16(            \
            af[i][1], bf[n][1], acc[2 * (Q) + i][n], 0, 0, 0);                    \
      }                                                                           \
    __builtin_amdgcn_s_setprio(0);                                                \
    __builtin_amdgcn_s_barrier();                                                 \
  } while (0)

  const int NT = Kdim >> 6;
  // prologue: tile0 fully into buf0; B(1) into buf1. 12 loads; leave B(1)'s 4.
  STAGEH(0, 0, 0, gA);
  STAGEH(0, 0, 1, gA + row128);
  STAGEH(0, 1, 0, gB);
  STAGEH(0, 1, 1, gB + row128);
  STAGEH(1, 1, 0, gB + 64);
  STAGEH(1, 1, 1, gB + row128 + 64);
  asm volatile("s_waitcnt vmcnt(4)" ::: "memory");
  __builtin_amdgcn_s_barrier();

  for (int t = 0; t < NT; ++t) {
    const int cur = t & 1;
    const unsigned short* bufA = sh + cur * 32768;
    const unsigned short* bufB = bufA + 16384;
    bf16x8 bf[4][2];
    bf16x8 af[2][2];
    // B-frags for the whole K-tile
#pragma unroll
    for (int n = 0; n < 4; n++) {
      bf[n][0] = *(const bf16x8*)(bufB + brow + n * 1024 + pc0);
      bf[n][1] = *(const bf16x8*)(bufB + brow + n * 1024 + pc1);
    }
    PHASEQ(0, if (t + 1 < NT) STAGEH(cur ^ 1, 0, 0, gA + (size_t)(t + 1) * 64), );
    PHASEQ(1, if (t + 1 < NT) STAGEH(cur ^ 1, 0, 1, gA + row128 + (size_t)(t + 1) * 64), );
    PHASEQ(2, if (t + 2 < NT) STAGEH(cur, 1, 0, gB + (size_t)(t + 2) * 64), );
    PHASEQ(3, if (t + 2 < NT) STAGEH(cur, 1, 1, gB + row128 + (size_t)(t + 2) * 64),
           if (t < NT - 2) { asm volatile("s_waitcnt vmcnt(4)" ::: "memory"); }
           else if (t == NT - 2) { asm volatile("s_waitcnt vmcnt(0)" ::: "memory"); });
  }
#undef STAGEH
#undef PHASEQ

  // 16x16 C/D layout: col = lane&15, row = (lane>>4)*4 + reg  [m89/m91]
#pragma unroll
  for (int m = 0; m < 8; m++)
#pragma unroll
    for (int n = 0; n < 4; n++)
#pragma unroll
      for (int reg = 0; reg < 4; reg++) {
        int row = m0 + wm * 128 + m * 16 + lh4 * 4 + reg;
        int col = n0 + wn * 64 + n * 16 + rl;
        float v = acc[m][n][reg];
        if (OUT_BF16)
          ((unsigned short*)Cout)[(size_t)row * ldc + col] = f2bf(v);
        else
          ((float*)Cout)[(size_t)row * ldc + col] = v;
      }
}

// ---------------- RoPE + relayout: qkv rows (token, DQKV) -> (B, H, S, HD) -------------
__global__ void rope_kernel(const unsigned short* __restrict__ src, const float* __restrict__ fc,
                            const float* __restrict__ fs, unsigned short* __restrict__ dst,
                            int nheads, int hshift, float scale) {
  int idx = blockIdx.x * 256 + threadIdx.x;
  int f4 = idx & 15;
  int rest = idx >> 4;
  int hh = rest & (nheads - 1);
  int t = rest >> hshift;
  int s = t & (S_LEN - 1);
  int b = t >> 10;
  union { uint4 v; unsigned short u[8]; } in, out;
  in.v = *(const uint4*)(src + (size_t)t * DQKV + hh * HD + f4 * 8);
  union { float4 v; float f[4]; } c4, s4;
  c4.v = *(const float4*)(fc + s * 64 + f4 * 4);
  s4.v = *(const float4*)(fs + s * 64 + f4 * 4);
#pragma unroll
  for (int j = 0; j < 4; j++) {
    float xr = bf2f(in.u[2 * j]), xi = bf2f(in.u[2 * j + 1]);
    float cc = c4.f[j], ss = s4.f[j];
    out.u[2 * j] = f2bf((xr * cc - xi * ss) * scale);
    out.u[2 * j + 1] = f2bf((xr * ss + xi * cc) * scale);
  }
  *(uint4*)(dst + ((size_t)(b * nheads + hh) * S_LEN + s) * HD + f4 * 8) = out.v;
}

// ---------------- V transpose: qkv V cols (token, kvh*HD+d) -> Vt (B,KVH,HD,S) ----------
__global__ void vtrans_kernel(const unsigned short* __restrict__ src, unsigned short* __restrict__ Vt) {
  __shared__ __align__(16) unsigned short tile[32][33];
  int s0 = blockIdx.x * 32, d0 = blockIdx.y * 32, bk = blockIdx.z;
  int tx = threadIdx.x & 31, ty = threadIdx.x >> 5;
#pragma unroll
  for (int i = 0; i < 4; i++) {
    int s = ty + i * 8;
    tile[s][tx] = src[(size_t)((bk >> 3) * S_LEN + s0 + s) * DQKV + (bk & 7) * HD + d0 + tx];
  }
  __syncthreads();
#pragma unroll
  for (int i = 0; i < 4; i++) {
    int d = ty + i * 8;
    Vt[((size_t)bk * HD + d0 + d) * S_LEN + s0 + tx] = tile[tx][d];
  }
}

// ---------------- flash attention (non-causal, full 1024 keys) ----------------
// De-staged (m169 / common-mistake #7): per (b,kvh) K+V = 512 KB, shared by 64
// blocks -> fully L2-resident. K and V fragments are read DIRECTLY from global
// (lane pattern coalesces into 16 x 64B-line requests per instruction, 4 lanes
// per line). No LDS staging, no async16, ZERO barriers in the k-loop (Pl is
// per-wave; same-wave LDS RAW/WAR ordering is handled by compiler lgkmcnt).
// Waves free-run; ~12 waves/CU TLP hides L2 latency (~200-300 cyc).
__global__ __launch_bounds__(256, 3) void attn_kernel(
    const unsigned short* __restrict__ Qb,  // (B,NH,S,HD)
    const unsigned short* __restrict__ Kb,  // (B,KVH,S,HD)
    const unsigned short* __restrict__ Vt,  // (B,KVH,HD,S)
    unsigned short* __restrict__ Ob) {      // (token, NH*HD)
  __shared__ __align__(16) unsigned short Pl[4][16][72]; // per-wave [q][key], padded
  const int tid = threadIdx.x, wave = tid >> 6, lane = tid & 63;
  const int qb = blockIdx.x, h = blockIdx.y, b = blockIdx.z;
  const int kvh = h >> 2;  // N_REP = 4
  const int lql = lane & 15, lqh = lane >> 4;
  const int qrow = qb * 64 + wave * 16;

  const unsigned short* Qp = Qb + ((size_t)(b * NH + h) * S_LEN + qrow + lql) * HD + lqh * 8;
  bf16x8 qf[4];
#pragma unroll
  for (int kd = 0; kd < 4; kd++) qf[kd] = *(const bf16x8*)(Qp + kd * 32);

  // per-lane operand bases:
  // K frag (ni,kd): row kt+ni*16+lql, d-bytes (kd*4+lqh)*16
  const unsigned short* Kp = Kb + (size_t)(b * KVH + kvh) * S_LEN * HD + (size_t)lql * HD + lqh * 8;
  // V frag (ni,ks): row d = ni*16+lql, key kt + (ks*4+lqh)*8
  const unsigned short* Vp = Vt + (size_t)(b * KVH + kvh) * HD * S_LEN + (size_t)lql * S_LEN + lqh * 8;

  float m_run[4], l_run[4];
  f32x4 Oacc[8] = {};
#pragma unroll
  for (int r = 0; r < 4; r++) { m_run[r] = -3.0e38f; l_run[r] = 0.0f; }

  for (int kt = 0; kt < S_LEN; kt += 64) {
    f32x4 sf[4] = {};
#pragma unroll
    for (int ni = 0; ni < 4; ni++) {
#pragma unroll
      for (int kd = 0; kd < 4; kd++) {
        bf16x8 kf = *(const bf16x8*)(Kp + (size_t)(kt + ni * 16) * HD + kd * 32);
        sf[ni] = __builtin_amdgcn_mfma_f32_16x16x32_bf16(qf[kd], kf, sf[ni], 0, 0, 0);
      }
    }
    float mnew[4], alpha[4], psum[4];
#pragma unroll
    for (int r = 0; r < 4; r++) {
      float v = fmaxf(fmaxf(sf[0][r], sf[1][r]), fmaxf(sf[2][r], sf[3][r]));
      v = fmaxf(v, __shfl_xor(v, 1));
      v = fmaxf(v, __shfl_xor(v, 2));
      v = fmaxf(v, __shfl_xor(v, 4));
      v = fmaxf(v, __shfl_xor(v, 8));
      mnew[r] = fmaxf(m_run[r], v);
      alpha[r] = ex2(m_run[r] - mnew[r]);
      m_run[r] = mnew[r];
      psum[r] = 0.0f;
    }
#pragma unroll
    for (int ni = 0; ni < 4; ni++)
#pragma unroll
      for (int r = 0; r < 4; r++) {
        float p = ex2(sf[ni][r] - mnew[r]);
        psum[r] += p;
        union { float f; uint32_t u; } pv; pv.f = p;
        Pl[wave][lqh * 4 + r][ni * 16 + lql] = (unsigned short)(pv.u >> 16);
      }
#pragma unroll
    for (int r = 0; r < 4; r++) {
      float v = psum[r];
      v += __shfl_xor(v, 1);
      v += __shfl_xor(v, 2);
      v += __shfl_xor(v, 4);
      v += __shfl_xor(v, 8);
      l_run[r] = l_run[r] * alpha[r] + v;
    }
#pragma unroll
    for (int ni = 0; ni < 8; ni++)
#pragma unroll
      for (int r = 0; r < 4; r++) Oacc[ni][r] *= alpha[r];
    bf16x8 pa[2];
#pragma unroll
    for (int ks = 0; ks < 2; ks++)
      pa[ks] = *(const bf16x8*)(&Pl[wave][lql][ks * 32 + lqh * 8]);
#pragma unroll
    for (int ni = 0; ni < 8; ni++) {
#pragma unroll
      for (int ks = 0; ks < 2; ks++) {
        bf16x8 vb = *(const bf16x8*)(Vp + (size_t)(ni * 16) * S_LEN + kt + ks * 32);
        Oacc[ni] = __builtin_amdgcn_mfma_f32_16x16x32_bf16(pa[ks], vb, Oacc[ni], 0, 0, 0);
      }
    }
  }
#pragma unroll
  for (int r = 0; r < 4; r++) l_run[r] = 1.0f / l_run[r];
#pragma unroll
  for (int ni = 0; ni < 8; ni++)
#pragma unroll
    for (int r = 0; r < 4; r++) {
      int q = qrow + lqh * 4 + r;
      Ob[(size_t)(b * S_LEN + q) * DIM + h * HD + ni * 16 + lql] = f2bf(Oacc[ni][r] * l_run[r]);
    }
}

extern "C" void kernel_launch(void* const* d_in, const int* in_sizes, int n_in,
                              void* d_out, int out_size, void* d_ws, size_t ws_size,
                              hipStream_t stream) {
  (void)in_sizes; (void)n_in; (void)out_size; (void)ws_size;
  const float* x  = (const float*)d_in[0];
  const float* fc = (const float*)d_in[1];
  const float* fs = (const float*)d_in[2];
  const float* wq = (const float*)d_in[3];
  const float* wk = (const float*)d_in[4];
  const float* wv = (const float*)d_in[5];
  const float* wo = (const float*)d_in[6];
  float* out = (float*)d_out;
  char* ws = (char*)d_ws;

  const size_t MB = 1024 * 1024;
  unsigned short* xb    = (unsigned short*)(ws + 0);         // 32MB; dead after gemm1
  unsigned short* attnb = (unsigned short*)(ws + 0);         // reuses xb slot
  unsigned short* wqkvt = (unsigned short*)(ws + 32 * MB);   // 48MB; dead after gemm1
  unsigned short* Qb    = (unsigned short*)(ws + 32 * MB);   // 32MB, reuses wqkvt
  unsigned short* Kb    = (unsigned short*)(ws + 64 * MB);   // 8MB
  unsigned short* Vt    = (unsigned short*)(ws + 72 * MB);   // 8MB
  unsigned short* wot   = (unsigned short*)(ws + 80 * MB);   // 32MB
  unsigned short* qkv   = (unsigned short*)(ws + 112 * MB);  // 48MB

  cvt_x_kernel<<<16384, 256, 0, stream>>>(x, xb);
  wtrans_kernel<<<dim3(64, 64), 256, 0, stream>>>(wq, wqkvt, 4096);
  wtrans_kernel<<<dim3(16, 64), 256, 0, stream>>>(wk, wqkvt + (size_t)4096 * 4096, 1024);
  wtrans_kernel<<<dim3(16, 64), 256, 0, stream>>>(wv, wqkvt + (size_t)5120 * 4096, 1024);
  wtrans_kernel<<<dim3(64, 64), 256, 0, stream>>>(wo, wot, 4096);
  // QKV projection: (4096 x 4096) @ (4096 x 6144) -> bf16; grid 24x16=384 (%8==0)
  gemm256_kernel<true><<<dim3(DQKV / 256, 16), 512, 0, stream>>>(xb, wqkvt, qkv, DIM, DQKV);
  // RoPE + relayout; Q scale = (1/sqrt(128)) * log2(e) for log2-domain softmax
  rope_kernel<<<8192, 256, 0, stream>>>(qkv, fc, fs, Qb, NH, 5, 0.12751879505099168f);
  rope_kernel<<<2048, 256, 0, stream>>>(qkv + 4096, fc, fs, Kb, KVH, 3, 1.0f);
  vtrans_kernel<<<dim3(32, 4, 32), 256, 0, stream>>>(qkv + 5120, Vt);
  // attention (barrier-free, L2-direct K/V)
  attn_kernel<<<dim3(16, NH, B_SZ), 256, 0, stream>>>(Qb, Kb, Vt, attnb);
  // out projection: fp32 out; grid 16x16=256 (%8==0)
  gemm256_kernel<false><<<dim3(16, 16), 512, 0, stream>>>(attnb, wot, out, DIM, DIM);
}

// Round 6
// 752.165 us; speedup vs baseline: 1.4948x; 1.4948x over previous
//
#include <hip/hip_runtime.h>
#include <cstdint>

#define B_SZ 4
#define S_LEN 1024
#define DIM 4096
#define NH 32
#define KVH 8
#define HD 128
#define DQKV 6144  // 4096 Q + 1024 K + 1024 V

typedef __bf16 bf16x8 __attribute__((ext_vector_type(8)));
typedef float f32x4 __attribute__((ext_vector_type(4)));

__device__ __forceinline__ unsigned short f2bf(float f) {
  union { float f; uint32_t u; } v; v.f = f;
  uint32_t u = v.u;
  return (unsigned short)((u + 0x7fffu + ((u >> 16) & 1u)) >> 16);
}
__device__ __forceinline__ float bf2f(unsigned short h) {
  union { uint32_t u; float f; } v; v.u = ((uint32_t)h) << 16;
  return v.f;
}
__device__ __forceinline__ float ex2(float x) {
#if __has_builtin(__builtin_amdgcn_exp2f)
  return __builtin_amdgcn_exp2f(x);
#else
  return exp2f(x);
#endif
}

// async global->LDS, 16B per lane; LDS dest = wave-uniform base + lane*16
__device__ __forceinline__ void async16(void* lds, const void* g) {
  __builtin_amdgcn_global_load_lds(
      (const __attribute__((address_space(1))) void*)g,
      (__attribute__((address_space(3))) void*)lds, 16, 0, 0);
}

// ---------------- elementwise f32 -> bf16 ----------------
__global__ void cvt_x_kernel(const float* __restrict__ x, unsigned short* __restrict__ xb) {
  size_t i = ((size_t)blockIdx.x * 256 + threadIdx.x) * 4;
  float4 v = *(const float4*)(x + i);
  ushort4 o;
  o.x = f2bf(v.x); o.y = f2bf(v.y); o.z = f2bf(v.z); o.w = f2bf(v.w);
  *(ushort4*)(xb + i) = o;
}

// ---------------- weight transpose+convert: w (K x N f32) -> wt (N x K bf16, ld=4096) ----
__global__ void wtrans_kernel(const float* __restrict__ w, unsigned short* __restrict__ wt, int N) {
  __shared__ float tile[64][65];
  int n0 = blockIdx.x * 64, k0 = blockIdx.y * 64;
  int tx = threadIdx.x & 63, ty = threadIdx.x >> 6;
#pragma unroll
  for (int i = 0; i < 16; i++) {
    int k = ty + i * 4;
    tile[k][tx] = w[(size_t)(k0 + k) * N + n0 + tx];
  }
  __syncthreads();
  int c = threadIdx.x & 31, ny = threadIdx.x >> 5;
#pragma unroll
  for (int i = 0; i < 8; i++) {
    int n = ny + i * 8;
    ushort2 o;
    o.x = f2bf(tile[2 * c][n]);
    o.y = f2bf(tile[2 * c + 1][n]);
    *(ushort2*)(wt + (size_t)(n0 + n) * DIM + k0 + 2 * c) = o;
  }
}

// ---------------- GEMM: C(MxN) = A(MxK bf16) * Bt(NxK bf16)^T ----------------
// m201-style 8-phase schedule (round-2 variant, best measured: 245 us QKV).
// 256x256 tile, BK=64, double-buffered 128 KiB LDS, 8 waves (2M x 4N).
template <bool OUT_BF16>
__global__ __launch_bounds__(512, 2) void gemm256_kernel(
    const unsigned short* __restrict__ A, const unsigned short* __restrict__ Bt,
    void* __restrict__ Cout, int Kdim, int ldc) {
  __shared__ __align__(16) unsigned short sh[2 * 32768];  // [buf][A 16384 | B 16384]
  const int tid = threadIdx.x;
  const int wave = tid >> 6, lane = tid & 63;
  // XCD-aware bijective block swizzle (grid size % 8 == 0 for both call sites)
  const int nbx = gridDim.x;
  const int nb = nbx * (int)gridDim.y;
  const int bid = (int)blockIdx.y * nbx + (int)blockIdx.x;
  const int sb = (bid & 7) * (nb >> 3) + (bid >> 3);
  const int m0 = (sb / nbx) * 256, n0 = (sb % nbx) * 256;

  // staging: half-tile = 128 rows x 64 elems = 1024 x 16B slots; thread covers
  // slot tid (j=0) and tid+512 (j=1). row = slot>>3, phys chunk = slot&7,
  // logical chunk = phys ^ (row&7). j=1 is row+64, same chunk bits.
  const int r0 = tid >> 3;                       // 0..63
  const int cs0 = (tid & 7) ^ (r0 & 7);
  const unsigned short* gA = A + (size_t)(m0 + r0) * Kdim + cs0 * 8;
  const unsigned short* gB = Bt + (size_t)(n0 + r0) * Kdim + cs0 * 8;
  const size_t row64 = (size_t)64 * Kdim;
  const size_t row128 = (size_t)128 * Kdim;

  // compute-side fragment addressing (16x16x32: lane row = lane&15, k-chunk = lane>>4)
  const int wm = wave >> 2, wn = wave & 3;
  const int rl = lane & 15, lh4 = lane >> 4;
  const int pc0 = (lh4 ^ (rl & 7)) * 8;          // k-half 0 phys chunk (elems)
  const int pc1 = ((lh4 + 4) ^ (rl & 7)) * 8;    // k-half 1 ( = pc0 ^ 32 )
  const int arow = (wm * 128 + rl) * 64;
  const int brow = (wn * 64 + rl) * 64;

  f32x4 acc[8][4] = {};

#define STAGEH(BUF, AB, H, GS) do {                                               \
    unsigned short* d_ = sh + (BUF) * 32768 + (AB) * 16384 + (H) * 8192 + wave * 512; \
    async16(d_, (GS));                                                            \
    async16(d_ + 4096, (GS) + row64);                                             \
  } while (0)

#define PHASEQ(Q, STAGE_STMT, WAIT_STMT) do {                                     \
    af[0][0] = *(const bf16x8*)(bufA + arow + (2 * (Q)) * 1024 + pc0);            \
    af[0][1] = *(const bf16x8*)(bufA + arow + (2 * (Q)) * 1024 + pc1);            \
    af[1][0] = *(const bf16x8*)(bufA + arow + (2 * (Q) + 1) * 1024 + pc0);        \
    af[1][1] = *(const bf16x8*)(bufA + arow + (2 * (Q) + 1) * 1024 + pc1);        \
    STAGE_STMT;                                                                   \
    WAIT_STMT;                                                                    \
    __builtin_amdgcn_s_barrier();                                                 \
    __builtin_amdgcn_s_setprio(1);                                                \
    _Pragma("unroll") for (int i = 0; i < 2; i++)                                 \
      _Pragma("unroll") for (int n = 0; n < 4; n++) {                             \
        acc[2 * (Q) + i][n] = __builtin_amdgcn_mfma_f32_16x16x32_bf16(            \
            af[i][0], bf[n][0], acc[2 * (Q) + i][n], 0, 0, 0);                    \
        acc[2 * (Q) + i][n] = __builtin_amdgcn_mfma_f32_16x16x32_bf16(            \
            af[i][1], bf[n][1], acc[2 * (Q) + i][n], 0, 0, 0);                    \
      }                                                                           \
    __builtin_amdgcn_s_setprio(0);                                                \
    __builtin_amdgcn_s_barrier();                                                 \
  } while (0)

  const int NT = Kdim >> 6;
  // prologue: tile0 fully into buf0; B(1) into buf1. 12 loads; leave B(1)'s 4.
  STAGEH(0, 0, 0, gA);
  STAGEH(0, 0, 1, gA + row128);
  STAGEH(0, 1, 0, gB);
  STAGEH(0, 1, 1, gB + row128);
  STAGEH(1, 1, 0, gB + 64);
  STAGEH(1, 1, 1, gB + row128 + 64);
  asm volatile("s_waitcnt vmcnt(4)" ::: "memory");
  __builtin_amdgcn_s_barrier();

  for (int t = 0; t < NT; ++t) {
    const int cur = t & 1;
    const unsigned short* bufA = sh + cur * 32768;
    const unsigned short* bufB = bufA + 16384;
    bf16x8 bf[4][2];
    bf16x8 af[2][2];
    // B-frags for the whole K-tile
#pragma unroll
    for (int n = 0; n < 4; n++) {
      bf[n][0] = *(const bf16x8*)(bufB + brow + n * 1024 + pc0);
      bf[n][1] = *(const bf16x8*)(bufB + brow + n * 1024 + pc1);
    }
    PHASEQ(0, if (t + 1 < NT) STAGEH(cur ^ 1, 0, 0, gA + (size_t)(t + 1) * 64), );
    PHASEQ(1, if (t + 1 < NT) STAGEH(cur ^ 1, 0, 1, gA + row128 + (size_t)(t + 1) * 64), );
    PHASEQ(2, if (t + 2 < NT) STAGEH(cur, 1, 0, gB + (size_t)(t + 2) * 64), );
    PHASEQ(3, if (t + 2 < NT) STAGEH(cur, 1, 1, gB + row128 + (size_t)(t + 2) * 64),
           if (t < NT - 2) { asm volatile("s_waitcnt vmcnt(4)" ::: "memory"); }
           else if (t == NT - 2) { asm volatile("s_waitcnt vmcnt(0)" ::: "memory"); });
  }
#undef STAGEH
#undef PHASEQ

  // 16x16 C/D layout: col = lane&15, row = (lane>>4)*4 + reg  [m89/m91]
#pragma unroll
  for (int m = 0; m < 8; m++)
#pragma unroll
    for (int n = 0; n < 4; n++)
#pragma unroll
      for (int reg = 0; reg < 4; reg++) {
        int row = m0 + wm * 128 + m * 16 + lh4 * 4 + reg;
        int col = n0 + wn * 64 + n * 16 + rl;
        float v = acc[m][n][reg];
        if (OUT_BF16)
          ((unsigned short*)Cout)[(size_t)row * ldc + col] = f2bf(v);
        else
          ((float*)Cout)[(size_t)row * ldc + col] = v;
      }
}

// ---------------- RoPE + relayout: qkv rows (token, DQKV) -> (B, H, S, HD) -------------
__global__ void rope_kernel(const unsigned short* __restrict__ src, const float* __restrict__ fc,
                            const float* __restrict__ fs, unsigned short* __restrict__ dst,
                            int nheads, int hshift, float scale) {
  int idx = blockIdx.x * 256 + threadIdx.x;
  int f4 = idx & 15;
  int rest = idx >> 4;
  int hh = rest & (nheads - 1);
  int t = rest >> hshift;
  int s = t & (S_LEN - 1);
  int b = t >> 10;
  union { uint4 v; unsigned short u[8]; } in, out;
  in.v = *(const uint4*)(src + (size_t)t * DQKV + hh * HD + f4 * 8);
  union { float4 v; float f[4]; } c4, s4;
  c4.v = *(const float4*)(fc + s * 64 + f4 * 4);
  s4.v = *(const float4*)(fs + s * 64 + f4 * 4);
#pragma unroll
  for (int j = 0; j < 4; j++) {
    float xr = bf2f(in.u[2 * j]), xi = bf2f(in.u[2 * j + 1]);
    float cc = c4.f[j], ss = s4.f[j];
    out.u[2 * j] = f2bf((xr * cc - xi * ss) * scale);
    out.u[2 * j + 1] = f2bf((xr * ss + xi * cc) * scale);
  }
  *(uint4*)(dst + ((size_t)(b * nheads + hh) * S_LEN + s) * HD + f4 * 8) = out.v;
}

// ---------------- V transpose: qkv V cols (token, kvh*HD+d) -> Vt (B,KVH,HD,S) ----------
__global__ void vtrans_kernel(const unsigned short* __restrict__ src, unsigned short* __restrict__ Vt) {
  __shared__ __align__(16) unsigned short tile[32][33];
  int s0 = blockIdx.x * 32, d0 = blockIdx.y * 32, bk = blockIdx.z;
  int tx = threadIdx.x & 31, ty = threadIdx.x >> 5;
#pragma unroll
  for (int i = 0; i < 4; i++) {
    int s = ty + i * 8;
    tile[s][tx] = src[(size_t)((bk >> 3) * S_LEN + s0 + s) * DQKV + (bk & 7) * HD + d0 + tx];
  }
  __syncthreads();
#pragma unroll
  for (int i = 0; i < 4; i++) {
    int d = ty + i * 8;
    Vt[((size_t)bk * HD + d0 + d) * S_LEN + s0 + tx] = tile[tx][d];
  }
}

// ---------------- flash attention (non-causal, full 1024 keys) ----------------
// Staged K/V (round-3 structure) + T14 pipeline: K and V double-buffered in LDS;
// tile t+2 staged AFTER compute of tile t; counted vmcnt(8) + raw s_barrier at
// the top of each tile (never a post-issue vmcnt(0) drain - the round<=3 version
// paid a full drain right after issuing 8 async16, once per tile per wave).
// Buffer-release safety: all ds_reads of buf[cur] are consumed by MFMAs before
// the post-compute barrier (compiler inserts lgkmcnt waits before uses), so
// after that barrier no wave has pending reads of buf[cur]; staging may overwrite.
// Visibility: each wave waits vmcnt(8) (its own tile-t loads done) BEFORE the
// barrier, so after the barrier all waves' slices of tile t are complete.
__global__ __launch_bounds__(256, 2) void attn_kernel(
    const unsigned short* __restrict__ Qb,  // (B,NH,S,HD)
    const unsigned short* __restrict__ Kb,  // (B,KVH,S,HD)
    const unsigned short* __restrict__ Vt,  // (B,KVH,HD,S)
    unsigned short* __restrict__ Ob) {      // (token, NH*HD)
  __shared__ __align__(16) unsigned short Kt[2][64][128];   // [buf][key][d-chunks, xor-swz]
  __shared__ __align__(16) unsigned short Vl[2][128][64];   // [buf][d][key-chunks, xor-swz]
  __shared__ __align__(16) unsigned short Pl[4][16][72];    // per-wave [q][key], padded
  const int tid = threadIdx.x, wave = tid >> 6, lane = tid & 63;
  const int qb = blockIdx.x, h = blockIdx.y, b = blockIdx.z;
  const int kvh = h >> 2;  // N_REP = 4
  const int lql = lane & 15, lqh = lane >> 4;
  const int qrow = qb * 64 + wave * 16;

  const unsigned short* Qp = Qb + ((size_t)(b * NH + h) * S_LEN + qrow + lql) * HD + lqh * 8;
  bf16x8 qf[4];
#pragma unroll
  for (int kd = 0; kd < 4; kd++) qf[kd] = *(const bf16x8*)(Qp + kd * 32);

  const unsigned short* Kp = Kb + (size_t)(b * KVH + kvh) * S_LEN * HD;
  const unsigned short* Vp = Vt + (size_t)(b * KVH + kvh) * HD * S_LEN;
  const int krow_in = lane >> 4;               // +0..3 within 4-row group
  const int kcol_sw = lane & 15;               // physical chunk
  const int vrow_in = lane >> 3;               // +0..7 within 8-row group
  const int vcol_off = ((lane & 7) ^ (lane >> 3)) * 8;

#define STAGE_KV(BB, KT) do {                                                       \
    _Pragma("unroll")                                                               \
    for (int j = 0; j < 4; j++) {                                                   \
      int rbase = wave * 16 + j * 4;                                                \
      int r = rbase + krow_in;                                                      \
      async16(&Kt[BB][rbase][0], Kp + (size_t)((KT) + r) * HD + ((kcol_sw ^ (r & 7)) * 8)); \
    }                                                                               \
    _Pragma("unroll")                                                               \
    for (int j = 0; j < 4; j++) {                                                   \
      int dbase = wave * 32 + j * 8;                                                \
      int d = dbase + vrow_in;                                                      \
      async16(&Vl[BB][dbase][0], Vp + (size_t)d * S_LEN + (KT) + vcol_off);         \
    }                                                                               \
  } while (0)

  float m_run[4], l_run[4];
  f32x4 Oacc[8] = {};
#pragma unroll
  for (int r = 0; r < 4; r++) { m_run[r] = -3.0e38f; l_run[r] = 0.0f; }

  // prologue: tiles 0 and 1 in flight (16 loads/wave)
  STAGE_KV(0, 0);
  STAGE_KV(1, 64);

  const int NKV = S_LEN / 64;  // 16
  for (int ti = 0; ti < NKV; ++ti) {
    const int cur = ti & 1;
    if (ti < NKV - 1) { asm volatile("s_waitcnt vmcnt(8)" ::: "memory"); }
    else              { asm volatile("s_waitcnt vmcnt(0)" ::: "memory"); }
    __builtin_amdgcn_s_barrier();

    const int kt = ti * 64;
    f32x4 sf[4] = {};
    __builtin_amdgcn_s_setprio(1);
#pragma unroll
    for (int ni = 0; ni < 4; ni++) {
      const int ksw = lql & 7;
#pragma unroll
      for (int kd = 0; kd < 4; kd++) {
        bf16x8 kf = *(const bf16x8*)(&Kt[cur][ni * 16 + lql][((kd * 4 + lqh) ^ ksw) * 8]);
        sf[ni] = __builtin_amdgcn_mfma_f32_16x16x32_bf16(qf[kd], kf, sf[ni], 0, 0, 0);
      }
    }
    __builtin_amdgcn_s_setprio(0);
    float mnew[4], alpha[4], psum[4];
#pragma unroll
    for (int r = 0; r < 4; r++) {
      float v = fmaxf(fmaxf(sf[0][r], sf[1][r]), fmaxf(sf[2][r], sf[3][r]));
      v = fmaxf(v, __shfl_xor(v, 1));
      v = fmaxf(v, __shfl_xor(v, 2));
      v = fmaxf(v, __shfl_xor(v, 4));
      v = fmaxf(v, __shfl_xor(v, 8));
      mnew[r] = fmaxf(m_run[r], v);
      alpha[r] = ex2(m_run[r] - mnew[r]);
      m_run[r] = mnew[r];
      psum[r] = 0.0f;
    }
#pragma unroll
    for (int ni = 0; ni < 4; ni++)
#pragma unroll
      for (int r = 0; r < 4; r++) {
        float p = ex2(sf[ni][r] - mnew[r]);
        psum[r] += p;
        union { float f; uint32_t u; } pv; pv.f = p;
        Pl[wave][lqh * 4 + r][ni * 16 + lql] = (unsigned short)(pv.u >> 16);
      }
#pragma unroll
    for (int r = 0; r < 4; r++) {
      float v = psum[r];
      v += __shfl_xor(v, 1);
      v += __shfl_xor(v, 2);
      v += __shfl_xor(v, 4);
      v += __shfl_xor(v, 8);
      l_run[r] = l_run[r] * alpha[r] + v;
    }
#pragma unroll
    for (int ni = 0; ni < 8; ni++)
#pragma unroll
      for (int r = 0; r < 4; r++) Oacc[ni][r] *= alpha[r];
    bf16x8 pa[2];
#pragma unroll
    for (int ks = 0; ks < 2; ks++)
      pa[ks] = *(const bf16x8*)(&Pl[wave][lql][ks * 32 + lqh * 8]);
    __builtin_amdgcn_s_setprio(1);
#pragma unroll
    for (int ni = 0; ni < 8; ni++) {
      const int ksw = lql & 7;
#pragma unroll
      for (int ks = 0; ks < 2; ks++) {
        bf16x8 vb = *(const bf16x8*)(&Vl[cur][ni * 16 + lql][((ks * 4 + lqh) ^ ksw) * 8]);
        Oacc[ni] = __builtin_amdgcn_mfma_f32_16x16x32_bf16(pa[ks], vb, Oacc[ni], 0, 0, 0);
      }
    }
    __builtin_amdgcn_s_setprio(0);

    __builtin_amdgcn_s_barrier();            // all waves done reading buf[cur]
    if (ti + 2 < NKV) STAGE_KV(cur, kt + 128);  // overwrite released buffer
  }
#undef STAGE_KV

#pragma unroll
  for (int r = 0; r < 4; r++) l_run[r] = 1.0f / l_run[r];
#pragma unroll
  for (int ni = 0; ni < 8; ni++)
#pragma unroll
    for (int r = 0; r < 4; r++) {
      int q = qrow + lqh * 4 + r;
      Ob[(size_t)(b * S_LEN + q) * DIM + h * HD + ni * 16 + lql] = f2bf(Oacc[ni][r] * l_run[r]);
    }
}

extern "C" void kernel_launch(void* const* d_in, const int* in_sizes, int n_in,
                              void* d_out, int out_size, void* d_ws, size_t ws_size,
                              hipStream_t stream) {
  (void)in_sizes; (void)n_in; (void)out_size; (void)ws_size;
  const float* x  = (const float*)d_in[0];
  const float* fc = (const float*)d_in[1];
  const float* fs = (const float*)d_in[2];
  const float* wq = (const float*)d_in[3];
  const float* wk = (const float*)d_in[4];
  const float* wv = (const float*)d_in[5];
  const float* wo = (const float*)d_in[6];
  float* out = (float*)d_out;
  char* ws = (char*)d_ws;

  const size_t MB = 1024 * 1024;
  unsigned short* xb    = (unsigned short*)(ws + 0);         // 32MB; dead after gemm1
  unsigned short* attnb = (unsigned short*)(ws + 0);         // reuses xb slot
  unsigned short* wqkvt = (unsigned short*)(ws + 32 * MB);   // 48MB; dead after gemm1
  unsigned short* Qb    = (unsigned short*)(ws + 32 * MB);   // 32MB, reuses wqkvt
  unsigned short* Kb    = (unsigned short*)(ws + 64 * MB);   // 8MB
  unsigned short* Vt    = (unsigned short*)(ws + 72 * MB);   // 8MB
  unsigned short* wot   = (unsigned short*)(ws + 80 * MB);   // 32MB
  unsigned short* qkv   = (unsigned short*)(ws + 112 * MB);  // 48MB

  cvt_x_kernel<<<16384, 256, 0, stream>>>(x, xb);
  wtrans_kernel<<<dim3(64, 64), 256, 0, stream>>>(wq, wqkvt, 4096);
  wtrans_kernel<<<dim3(16, 64), 256, 0, stream>>>(wk, wqkvt + (size_t)4096 * 4096, 1024);
  wtrans_kernel<<<dim3(16, 64), 256, 0, stream>>>(wv, wqkvt + (size_t)5120 * 4096, 1024);
  wtrans_kernel<<<dim3(64, 64), 256, 0, stream>>>(wo, wot, 4096);
  // QKV projection: (4096 x 4096) @ (4096 x 6144) -> bf16; grid 24x16=384 (%8==0)
  gemm256_kernel<true><<<dim3(DQKV / 256, 16), 512, 0, stream>>>(xb, wqkvt, qkv, DIM, DQKV);
  // RoPE + relayout; Q scale = (1/sqrt(128)) * log2(e) for log2-domain softmax
  rope_kernel<<<8192, 256, 0, stream>>>(qkv, fc, fs, Qb, NH, 5, 0.12751879505099168f);
  rope_kernel<<<2048, 256, 0, stream>>>(qkv + 4096, fc, fs, Kb, KVH, 3, 1.0f);
  vtrans_kernel<<<dim3(32, 4, 32), 256, 0, stream>>>(qkv + 5120, Vt);
  // attention (double-buffered staged K/V, counted vmcnt)
  attn_kernel<<<dim3(16, NH, B_SZ), 256, 0, stream>>>(Qb, Kb, Vt, attnb);
  // out projection: fp32 out; grid 16x16=256 (%8==0)
  gemm256_kernel<false><<<dim3(16, 16), 512, 0, stream>>>(attnb, wot, out, DIM, DIM);
}